// Round 3
// baseline (323.212 us; speedup 1.0000x reference)
//
#include <hip/hip_runtime.h>

typedef float f32x4 __attribute__((ext_vector_type(4)));
typedef short s16x8 __attribute__((ext_vector_type(8)));
typedef short s16x4 __attribute__((ext_vector_type(4)));
typedef int   i32x4 __attribute__((ext_vector_type(4)));

using abfrag = s16x8;  // 8 bf16 = 4 VGPRs

#define DI __device__ __forceinline__

DI unsigned short f2bf(float x) {  // RNE float->bf16
  unsigned u = __builtin_bit_cast(unsigned, x);
  u += 0x7fffu + ((u >> 16) & 1u);
  return (unsigned short)(u >> 16);
}
DI float bf2f(unsigned short h) {
  return __builtin_bit_cast(float, ((unsigned)h) << 16);
}

DI f32x4 MFMA(abfrag a, abfrag b, f32x4 c) {
  return __builtin_amdgcn_mfma_f32_16x16x32_bf16(a, b, c, 0, 0, 0);
}

// async global->LDS DMA, 16B/lane; dest = uniform base + lane*16 (m104);
// per-lane source carries the swizzle (m173).
DI void gld16(void* lds_base, const void* gsrc) {
  __builtin_amdgcn_global_load_lds(
      (const __attribute__((address_space(1))) unsigned int*)gsrc,
      (__attribute__((address_space(3))) unsigned int*)lds_base, 16, 0, 0);
}

// ---------------- fused fp32 -> bf16 conversion (4 sources, contiguous dst) --
__global__ void f2bf_multi(const float* __restrict__ s0, int n0,
                           const float* __restrict__ s1, int n1,
                           const float* __restrict__ s2, int n2,
                           const float* __restrict__ s3, int n3,
                           unsigned short* __restrict__ dst) {
  const int total = n0 + n1 + n2 + n3;  // vec4 units
  int i = blockIdx.x * blockDim.x + threadIdx.x;
  const int stride = gridDim.x * blockDim.x;
  for (; i < total; i += stride) {
    const float* s; int off;
    if (i < n0) { s = s0; off = i; }
    else if (i < n0 + n1) { s = s1; off = i - n0; }
    else if (i < n0 + n1 + n2) { s = s2; off = i - n0 - n1; }
    else { s = s3; off = i - n0 - n1 - n2; }
    f32x4 v = ((const f32x4*)s)[off];
    s16x4 o;
#pragma unroll
    for (int j = 0; j < 4; ++j) o[j] = (short)f2bf(v[j]);
    ((s16x4*)dst)[i] = o;
  }
}

// ---------------- fused gml layer (R3: B direct from L2, h-only LDS) --------
// block = (n, 128-col chunk), 4 waves; wave wv owns cols [32wv,32wv+32), all 64
// rows; acc[4 groups][4 row-frags][2 col-frags]. W (B operand) is loaded
// straight from global (L2-resident) into registers -- no LDS staging.
// h staged in LDS (8KB/kt tile, double-buffered, ds_write + raw barriers, no
// vmcnt drain). G staged via gld16 at kernel start into its own region.
template <int C, bool RES>
__global__ __launch_bounds__(256, 2) void gml_layer_kernel(
    const unsigned short* __restrict__ hin,   // [128][64][C] bf16
    const unsigned short* __restrict__ Wb,    // [4][512][C] bf16
    const float* __restrict__ bias,           // [4][512]
    const unsigned short* __restrict__ Gb,    // [128][4][64][64] bf16
    unsigned short* __restrict__ hout) {      // [128][64][512] bf16
  constexpr int NT = C / 64;
  __shared__ short lh[2][64][64];  // 16 KB, XOR slot-swizzled (slot ^= row&7)
  __shared__ short lg[4][64][64];  // 32 KB, swizzled via pre-swizzled DMA src

  const int tid  = threadIdx.x;
  const int wv   = tid >> 6;
  const int lane = tid & 63;
  const int l15  = tid & 15;
  const int l7   = l15 & 7;
  const int gq   = (tid >> 4) & 3;
  const int n    = blockIdx.x & 127;
  const int pc0  = (blockIdx.x >> 7) * 128;
  const int lrow = lane >> 3;    // 0..7
  const int s8   = lane & 7;     // staging slot
  const int lsoff = ((s8 ^ lrow) << 3);  // swizzled element offset

  const unsigned short* hsrc = hin + (size_t)n * 64 * C;
  const unsigned short* gsrc = Gb + (size_t)(n * 4 + wv) * 4096;  // g = wv

  // ---- G DMA issued now, consumed after K-loop ----
#pragma unroll
  for (int j = 0; j < 8; ++j)
    gld16(&lg[wv][8 * j][0], gsrc + (8 * j + lrow) * 64 + lsoff);

  // ---- B addressing: SGPR base per (g,u), one per-lane offset VGPR ----
  const unsigned short* wgu[4][2];
#pragma unroll
  for (int g = 0; g < 4; ++g)
#pragma unroll
    for (int u = 0; u < 2; ++u)
      wgu[g][u] = Wb + (size_t)(g * 512 + pc0 + 16 * u) * C;
  const int loff = (32 * wv + l15) * C + gq * 8;  // per-lane

  // ---- acc init = bias ----
  f32x4 acc[4][4][2];
#pragma unroll
  for (int g = 0; g < 4; ++g)
#pragma unroll
    for (int u = 0; u < 2; ++u) {
      const float bv = bias[g * 512 + pc0 + 32 * wv + 16 * u + l15];
#pragma unroll
      for (int t = 0; t < 4; ++t) acc[g][t][u] = f32x4{bv, bv, bv, bv};
    }

  // ---- h staging prologue (kt = 0) ----
  const int hrow0 = 16 * wv + lrow;  // this wave writes rows hrow0, hrow0+8
  {
    i32x4 h0 = *(const i32x4*)(hsrc + (size_t)hrow0 * C + s8 * 8);
    i32x4 h1 = *(const i32x4*)(hsrc + (size_t)(hrow0 + 8) * C + s8 * 8);
    *(i32x4*)&lh[0][hrow0][lsoff] = h0;       // row&7 == lrow for both rows
    *(i32x4*)&lh[0][hrow0 + 8][lsoff] = h1;
  }

  i32x4 bcur[8], bnxt[8];
  auto loadB = [&](i32x4* d, int kt, int ks) {
#pragma unroll
    for (int g = 0; g < 4; ++g)
#pragma unroll
      for (int u = 0; u < 2; ++u)
        d[g * 2 + u] = *(const i32x4*)(wgu[g][u] + loff + kt * 64 + ks * 32);
  };
  loadB(bcur, 0, 0);
  asm volatile("s_waitcnt lgkmcnt(0)" ::: "memory");  // h tile 0 written

  for (int kt = 0; kt < NT; ++kt) {
    const int cur = kt & 1;
    i32x4 hA, hB;
    if (kt + 1 < NT) {  // next h tile -> regs (in flight across barrier)
      hA = *(const i32x4*)(hsrc + (size_t)hrow0 * C + (kt + 1) * 64 + s8 * 8);
      hB = *(const i32x4*)(hsrc + (size_t)(hrow0 + 8) * C + (kt + 1) * 64 + s8 * 8);
    }
    asm volatile("" ::: "memory");
    __builtin_amdgcn_s_barrier();   // h[cur] visible; readers of h[1-cur] done
    asm volatile("" ::: "memory");

    // ---- ks = 0 ----
    loadB(bnxt, kt, 1);
    {
      abfrag a[4];
#pragma unroll
      for (int t = 0; t < 4; ++t)
        a[t] = *(const abfrag*)&lh[cur][16 * t + l15][(gq ^ l7) << 3];
#pragma unroll
      for (int g = 0; g < 4; ++g)
#pragma unroll
        for (int u = 0; u < 2; ++u) {
          const abfrag b = __builtin_bit_cast(abfrag, bcur[g * 2 + u]);
#pragma unroll
          for (int t = 0; t < 4; ++t) acc[g][t][u] = MFMA(a[t], b, acc[g][t][u]);
        }
    }
    // ---- ks = 1 ----
    if (kt + 1 < NT) loadB(bcur, kt + 1, 0);
    {
      abfrag a[4];
#pragma unroll
      for (int t = 0; t < 4; ++t)
        a[t] = *(const abfrag*)&lh[cur][16 * t + l15][((4 + gq) ^ l7) << 3];
#pragma unroll
      for (int g = 0; g < 4; ++g)
#pragma unroll
        for (int u = 0; u < 2; ++u) {
          const abfrag b = __builtin_bit_cast(abfrag, bnxt[g * 2 + u]);
#pragma unroll
          for (int t = 0; t < 4; ++t) acc[g][t][u] = MFMA(a[t], b, acc[g][t][u]);
        }
    }
    if (kt + 1 < NT) {  // write next h tile to the other buffer
      *(i32x4*)&lh[1 - cur][hrow0][lsoff] = hA;
      *(i32x4*)&lh[1 - cur][hrow0 + 8][lsoff] = hB;
      asm volatile("s_waitcnt lgkmcnt(0)" ::: "memory");
    }
  }

  // ---- G ready? (DMA from kernel start) ----
  asm volatile("s_waitcnt vmcnt(0)" ::: "memory");
  __syncthreads();

  // ---- xo = G * multi per group; relu+max fused (identical to R2) ----
  f32x4 xmax[4][2];
#pragma unroll
  for (int t = 0; t < 4; ++t)
#pragma unroll
    for (int u = 0; u < 2; ++u) xmax[t][u] = f32x4{0.f, 0.f, 0.f, 0.f};

#pragma unroll
  for (int g = 0; g < 4; ++g) {
    // B-frags from acc[g] in-register; shared k-slot bijection:
    // step s, lane-group gq, slot i -> j = 16s + 4gq + (i&3) + 32*(i>>2)
    abfrag bb[2][2];
#pragma unroll
    for (int s = 0; s < 2; ++s)
#pragma unroll
      for (int u = 0; u < 2; ++u) {
        abfrag t8;
#pragma unroll
        for (int r = 0; r < 4; ++r) {
          t8[r]     = (short)f2bf(acc[g][s][u][r]);
          t8[4 + r] = (short)f2bf(acc[g][s + 2][u][r]);
        }
        bb[s][u] = t8;
      }
    f32x4 xg[4][2];
#pragma unroll
    for (int t = 0; t < 4; ++t)
#pragma unroll
      for (int u = 0; u < 2; ++u) xg[t][u] = f32x4{0.f, 0.f, 0.f, 0.f};
#pragma unroll
    for (int t = 0; t < 4; ++t) {
      const short* grow = &lg[g][16 * t + l15][0];
#pragma unroll
      for (int s = 0; s < 2; ++s) {
        const int slot = 2 * s + (gq >> 1);
        const int e1 = ((slot ^ l7) << 3) + ((gq & 1) << 2);
        const int e2 = (((slot + 4) ^ l7) << 3) + ((gq & 1) << 2);
        s16x4 alo = *(const s16x4*)(grow + e1);
        s16x4 ahi = *(const s16x4*)(grow + e2);
        abfrag a;
#pragma unroll
        for (int j = 0; j < 4; ++j) { a[j] = alo[j]; a[4 + j] = ahi[j]; }
#pragma unroll
        for (int u = 0; u < 2; ++u) xg[t][u] = MFMA(a, bb[s][u], xg[t][u]);
      }
    }
#pragma unroll
    for (int t = 0; t < 4; ++t)
#pragma unroll
      for (int u = 0; u < 2; ++u)
#pragma unroll
        for (int r = 0; r < 4; ++r)
          xmax[t][u][r] = fmaxf(xmax[t][u][r], xg[t][u][r]);  // init 0 => relu
  }

  // ---- residual + store (C/D layout m89: col=lane&15, row=(lane>>4)*4+reg) --
#pragma unroll
  for (int t = 0; t < 4; ++t)
#pragma unroll
    for (int u = 0; u < 2; ++u)
#pragma unroll
      for (int r = 0; r < 4; ++r) {
        const int m = 16 * t + 4 * gq + r;
        const int d = pc0 + 32 * wv + 16 * u + l15;
        float v = xmax[t][u][r];
        if constexpr (RES) v += bf2f(hin[(size_t)(n * 64 + m) * C + d]);
        hout[(size_t)(n * 64 + m) * 512 + d] = f2bf(v);
      }
}

// ---------------- final linear head (unchanged) ----------------
__global__ __launch_bounds__(256, 2) void final_kernel(
    const unsigned short* __restrict__ hin,  // [128][64][512] bf16
    const float* __restrict__ w1,            // [128][512]
    const float* __restrict__ b1,            // [128]
    const float* __restrict__ w2,            // [128]
    const float* __restrict__ b2,            // [1]
    float* __restrict__ out) {               // [128][64]
  constexpr int KT = 64, LW = 72, C = 512, NT = C / KT;
  __shared__ short sh_h[2][64][LW];
  __shared__ short sh_w[2][128][LW];
  __shared__ float red[4][64];
  const int tid = threadIdx.x;
  const int wv  = tid >> 6;
  const int l15 = tid & 15;
  const int gq  = (tid >> 4) & 3;
  const int n   = blockIdx.x;
  const int srow = tid >> 3;
  const int scol = (tid & 7) * 8;
  const unsigned short* hsrc = hin + (size_t)n * 64 * C;

  f32x4 acc[4][2];
#pragma unroll
  for (int t = 0; t < 4; ++t)
#pragma unroll
    for (int u = 0; u < 2; ++u) acc[t][u] = f32x4{0.f, 0.f, 0.f, 0.f};

  i32x4 hr[2], wr[4];
#pragma unroll
  for (int p = 0; p < 2; ++p)
    hr[p] = *(const i32x4*)(hsrc + (srow + p * 32) * C + scol);
#pragma unroll
  for (int p = 0; p < 4; ++p) {  // fp32 w1 -> bf16 in-stage
    const float* s = w1 + (srow + p * 32) * C + scol;
    f32x4 v0 = *(const f32x4*)s;
    f32x4 v1 = *(const f32x4*)(s + 4);
    s16x8 o;
#pragma unroll
    for (int j = 0; j < 4; ++j) { o[j] = (short)f2bf(v0[j]); o[4 + j] = (short)f2bf(v1[j]); }
    wr[p] = __builtin_bit_cast(i32x4, o);
  }
#pragma unroll
  for (int p = 0; p < 2; ++p) *(i32x4*)&sh_h[0][srow + p * 32][scol] = hr[p];
#pragma unroll
  for (int p = 0; p < 4; ++p) *(i32x4*)&sh_w[0][srow + p * 32][scol] = wr[p];

  for (int kt = 0; kt < NT; ++kt) {
    const int cur = kt & 1;
    if (kt + 1 < NT) {
#pragma unroll
      for (int p = 0; p < 2; ++p)
        hr[p] = *(const i32x4*)(hsrc + (srow + p * 32) * C + (kt + 1) * KT + scol);
#pragma unroll
      for (int p = 0; p < 4; ++p) {
        const float* s = w1 + (srow + p * 32) * C + (kt + 1) * KT + scol;
        f32x4 v0 = *(const f32x4*)s;
        f32x4 v1 = *(const f32x4*)(s + 4);
        s16x8 o;
#pragma unroll
        for (int j = 0; j < 4; ++j) { o[j] = (short)f2bf(v0[j]); o[4 + j] = (short)f2bf(v1[j]); }
        wr[p] = __builtin_bit_cast(i32x4, o);
      }
    }
    __syncthreads();
#pragma unroll
    for (int ks = 0; ks < 2; ++ks) {
      abfrag a[4], b[2];
#pragma unroll
      for (int t = 0; t < 4; ++t)
        a[t] = *(const abfrag*)&sh_h[cur][16 * t + l15][ks * 32 + gq * 8];
#pragma unroll
      for (int u = 0; u < 2; ++u)
        b[u] = *(const abfrag*)&sh_w[cur][32 * wv + 16 * u + l15][ks * 32 + gq * 8];
#pragma unroll
      for (int t = 0; t < 4; ++t)
#pragma unroll
        for (int u = 0; u < 2; ++u) acc[t][u] = MFMA(a[t], b[u], acc[t][u]);
    }
    if (kt + 1 < NT) {
#pragma unroll
      for (int p = 0; p < 2; ++p) *(i32x4*)&sh_h[1 - cur][srow + p * 32][scol] = hr[p];
#pragma unroll
      for (int p = 0; p < 4; ++p) *(i32x4*)&sh_w[1 - cur][srow + p * 32][scol] = wr[p];
    }
  }

  float b1v[2], w2v[2];
#pragma unroll
  for (int u = 0; u < 2; ++u) {
    b1v[u] = b1[32 * wv + 16 * u + l15];
    w2v[u] = w2[32 * wv + 16 * u + l15];
  }
  float part[4][4];
#pragma unroll
  for (int t = 0; t < 4; ++t)
#pragma unroll
    for (int r = 0; r < 4; ++r) {
      float s0 = 0.f;
#pragma unroll
      for (int u = 0; u < 2; ++u)
        s0 += fmaxf(acc[t][u][r] + b1v[u], 0.f) * w2v[u];
      part[t][r] = s0;
    }
#pragma unroll
  for (int t = 0; t < 4; ++t)
#pragma unroll
    for (int r = 0; r < 4; ++r)
#pragma unroll
      for (int msk = 1; msk < 16; msk <<= 1)
        part[t][r] += __shfl_xor(part[t][r], msk);
  if (l15 == 0) {
#pragma unroll
    for (int t = 0; t < 4; ++t)
#pragma unroll
      for (int r = 0; r < 4; ++r) red[wv][16 * t + 4 * gq + r] = part[t][r];
  }
  __syncthreads();
  if (tid < 64)
    out[(size_t)n * 64 + tid] =
        red[0][tid] + red[1][tid] + red[2][tid] + red[3][tid] + b2[0];
}

// ---------------- host ----------------
extern "C" void kernel_launch(void* const* d_in, const int* in_sizes, int n_in,
                              void* d_out, int out_size, void* d_ws, size_t ws_size,
                              hipStream_t stream) {
  const float* G   = (const float*)d_in[0];
  const float* x   = (const float*)d_in[1];
  const float* W0  = (const float*)d_in[2];
  const float* b0  = (const float*)d_in[3];
  const float* W   = (const float*)d_in[4];
  const float* b   = (const float*)d_in[5];
  const float* l1w = (const float*)d_in[6];
  const float* l1b = (const float*)d_in[7];
  const float* l2w = (const float*)d_in[8];
  const float* l2b = (const float*)d_in[9];
  float* out = (float*)d_out;

  char* p = (char*)d_ws;
  unsigned short* W0b = (unsigned short*)p; p += (size_t)4 * 512 * 128 * 2;
  unsigned short* Wb  = (unsigned short*)p; p += (size_t)7 * 4 * 512 * 512 * 2;
  unsigned short* Gb  = (unsigned short*)p; p += (size_t)128 * 4 * 64 * 64 * 2;
  unsigned short* xb  = (unsigned short*)p; p += (size_t)128 * 64 * 128 * 2;
  unsigned short* hA  = (unsigned short*)p; p += (size_t)128 * 64 * 512 * 2;
  unsigned short* hB  = (unsigned short*)p; p += (size_t)128 * 64 * 512 * 2;
  // total ws use: 38,273,024 bytes

  // one fused conversion: dsts (W0b,Wb,Gb,xb) are contiguous
  const int n0 = 4 * 512 * 128 / 4;
  const int n1 = 7 * 4 * 512 * 512 / 4;
  const int n2 = 128 * 4 * 64 * 64 / 4;
  const int n3 = 128 * 64 * 128 / 4;
  f2bf_multi<<<2048, 256, 0, stream>>>(W0, n0, W, n1, G, n2, x, n3, W0b);

  gml_layer_kernel<128, false><<<512, 256, 0, stream>>>(xb, W0b, b0, Gb, hA);
  const unsigned short* src = hA;
  unsigned short* dst = hB;
  for (int i = 0; i < 7; ++i) {
    gml_layer_kernel<512, true><<<512, 256, 0, stream>>>(
        src, Wb + (size_t)i * 4 * 512 * 512, b + (size_t)i * 4 * 512, Gb, dst);
    const unsigned short* t = src; src = dst; dst = (unsigned short*)t;
  }
  final_kernel<<<128, 256, 0, stream>>>(src, l1w, l1b, l2w, l2b, out);
}

// Round 4
// 246.298 us; speedup vs baseline: 1.3123x; 1.3123x over previous
//
#include <hip/hip_runtime.h>

typedef float f32x4 __attribute__((ext_vector_type(4)));
typedef short s16x8 __attribute__((ext_vector_type(8)));
typedef short s16x4 __attribute__((ext_vector_type(4)));
typedef int   i32x4 __attribute__((ext_vector_type(4)));

using abfrag = s16x8;  // 8 bf16 = 4 VGPRs

#define DI __device__ __forceinline__

DI unsigned short f2bf(float x) {  // RNE float->bf16
  unsigned u = __builtin_bit_cast(unsigned, x);
  u += 0x7fffu + ((u >> 16) & 1u);
  return (unsigned short)(u >> 16);
}
DI float bf2f(unsigned short h) {
  return __builtin_bit_cast(float, ((unsigned)h) << 16);
}

DI f32x4 MFMA(abfrag a, abfrag b, f32x4 c) {
  return __builtin_amdgcn_mfma_f32_16x16x32_bf16(a, b, c, 0, 0, 0);
}

// async global->LDS DMA, 16B/lane; LDS dest = uniform base + lane*16 (m104);
// per-lane source address carries the swizzle (m173).
DI void gld16(void* lds_base, const void* gsrc) {
  __builtin_amdgcn_global_load_lds(
      (const __attribute__((address_space(1))) unsigned int*)gsrc,
      (__attribute__((address_space(3))) unsigned int*)lds_base, 16, 0, 0);
}

#define MEMFENCE asm volatile("" ::: "memory")

// ---------------- fused fp32 -> bf16 conversion (4 sources, contiguous dst) --
__global__ void f2bf_multi(const float* __restrict__ s0, int n0,
                           const float* __restrict__ s1, int n1,
                           const float* __restrict__ s2, int n2,
                           const float* __restrict__ s3, int n3,
                           unsigned short* __restrict__ dst) {
  const int total = n0 + n1 + n2 + n3;  // vec4 units
  int i = blockIdx.x * blockDim.x + threadIdx.x;
  const int stride = gridDim.x * blockDim.x;
  for (; i < total; i += stride) {
    const float* s; int off;
    if (i < n0) { s = s0; off = i; }
    else if (i < n0 + n1) { s = s1; off = i - n0; }
    else if (i < n0 + n1 + n2) { s = s2; off = i - n0 - n1; }
    else { s = s3; off = i - n0 - n1 - n2; }
    f32x4 v = ((const f32x4*)s)[off];
    s16x4 o;
#pragma unroll
    for (int j = 0; j < 4; ++j) o[j] = (short)f2bf(v[j]);
    ((s16x4*)dst)[i] = o;
  }
}

// ---------------- fused gml layer (R4: 512-thr, W dbuf DMA pipeline) --------
// block = (2 n-values, 128-col chunk); 8 waves = 2 nl x 4 wv. Wave (nl,wv)
// computes rows 0..63 of n=2nn+nl, cols [pc0+32wv, +32), all 4 groups in acc.
// W double-buffered in LDS via global_load_lds, DMA for kt+1 issued one full
// kt ahead (counted waits, raw barriers -- no blanket vmcnt(0)+barrier drain).
// h tile (16KB) reg-staged, single-buffered. G DMA'd into retiring W buffer.
template <int C, bool RES>
__global__ __launch_bounds__(512, 2) void gml_layer_kernel(
    const unsigned short* __restrict__ hin,   // [128][64][C] bf16
    const unsigned short* __restrict__ Wb,    // [4][512][C] bf16
    const float* __restrict__ bias,           // [4][512]
    const unsigned short* __restrict__ Gb,    // [128][4][64][64] bf16
    unsigned short* __restrict__ hout) {      // [128][64][512] bf16
  constexpr int NT = C / 64;
  __shared__ short lh[2][64][64];        // [nl][row][col] 16 KB, XOR-swizzled
  __shared__ short lw[2][4][128][64];    // [buf][g][row][col] 128 KB
  auto lgv = (short(*)[4][64][64]) & lw[0][0][0][0];  // G overlay (buf0, 64KB)

  const int tid  = threadIdx.x;
  const int w    = tid >> 6;
  const int lane = tid & 63;
  const int l15  = lane & 15;
  const int l7   = l15 & 7;
  const int gq   = (lane >> 4) & 3;
  const int nl   = w >> 2;
  const int wv   = w & 3;
  const int nn   = blockIdx.x & 63;
  const int pc0  = (blockIdx.x >> 6) * 128;
  const int n    = nn * 2 + nl;
  const int lrow = lane >> 3;
  const int s8   = lane & 7;
  const int lsoff = ((s8 ^ lrow) << 3);  // swizzled element offset in 64-row

  const unsigned short* hsrc = hin + (size_t)n * 64 * C;
  const int widx = w * 8;

  // W tile kt -> lw[buf]: 64 x 1KB DMA instrs, 8 per wave
  auto stageW = [&](int buf, int kt) {
#pragma unroll
    for (int j = 0; j < 8; ++j) {
      const int idx = widx + j;
      const int g = idx >> 4, rb = idx & 15;
      gld16(&lw[buf][g][8 * rb][0],
            Wb + (size_t)(g * 512 + pc0 + 8 * rb + lrow) * C + kt * 64 + lsoff);
    }
  };
  // G [2nl][4g][64][64] -> buf0 overlay: 64 x 1KB, 8 per wave
  auto stageG = [&]() {
#pragma unroll
    for (int j = 0; j < 8; ++j) {
      const int idx = widx + j;
      const int ng = idx >> 3, rb = idx & 7;
      const int gnl = ng >> 2, gg = ng & 3;
      gld16(&lgv[gnl][gg][8 * rb][0],
            Gb + (size_t)((nn * 2 + gnl) * 4 + gg) * 4096 + (8 * rb + lrow) * 64 + lsoff);
    }
  };

  // ---- acc init = bias ----
  f32x4 acc[4][4][2];
#pragma unroll
  for (int g = 0; g < 4; ++g)
#pragma unroll
    for (int u = 0; u < 2; ++u) {
      const float bv = bias[g * 512 + pc0 + 32 * wv + 16 * u + l15];
#pragma unroll
      for (int t = 0; t < 4; ++t) acc[g][t][u] = f32x4{bv, bv, bv, bv};
    }

  // ---- prologue: W(0)->buf0, h(0)->regs, W(1)->buf1 ----
  const int hrow0 = 16 * wv + lrow;  // wave stages rows hrow0, hrow0+8 of its n
  stageW(0, 0);
  i32x4 h0 = *(const i32x4*)(hsrc + (size_t)hrow0 * C + s8 * 8);
  i32x4 h1 = *(const i32x4*)(hsrc + (size_t)(hrow0 + 8) * C + s8 * 8);
  stageW(1, 1);
  asm volatile("s_waitcnt vmcnt(8)" ::: "memory");  // W(0)+h landed; W(1) flies
  *(i32x4*)&lh[nl][hrow0][lsoff] = h0;
  *(i32x4*)&lh[nl][hrow0 + 8][lsoff] = h1;
  asm volatile("s_waitcnt lgkmcnt(0)" ::: "memory");
  __builtin_amdgcn_s_barrier();
  MEMFENCE;

  for (int kt = 0; kt < NT; ++kt) {
    const int cur = kt & 1;
    i32x4 hA, hB;
    if (kt + 1 < NT) {  // next h tile -> regs (flies during compute)
      hA = *(const i32x4*)(hsrc + (size_t)hrow0 * C + (kt + 1) * 64 + s8 * 8);
      hB = *(const i32x4*)(hsrc + (size_t)(hrow0 + 8) * C + (kt + 1) * 64 + s8 * 8);
    }
    // ---- compute on lh + lw[cur]: A-frags read once, reused over 4 groups --
#pragma unroll
    for (int ks = 0; ks < 2; ++ks) {
      const int so = ((4 * ks + gq) ^ l7) << 3;
      abfrag a[4];
#pragma unroll
      for (int t = 0; t < 4; ++t)
        a[t] = *(const abfrag*)&lh[nl][16 * t + l15][so];
#pragma unroll
      for (int g = 0; g < 4; ++g)
#pragma unroll
        for (int u = 0; u < 2; ++u) {
          const abfrag b = *(const abfrag*)&lw[cur][g][32 * wv + 16 * u + l15][so];
#pragma unroll
          for (int t = 0; t < 4; ++t) acc[g][t][u] = MFMA(a[t], b, acc[g][t][u]);
        }
    }
    MEMFENCE;
    __builtin_amdgcn_s_barrier();  // readers of lh & lw[cur] done
    MEMFENCE;
    if (kt + 1 < NT) {
      // drain: h regs (+W(kt+1), both ~1 full kt old -> near-free)
      asm volatile("s_waitcnt vmcnt(0)" ::: "memory");
      *(i32x4*)&lh[nl][hrow0][lsoff] = hA;
      *(i32x4*)&lh[nl][hrow0 + 8][lsoff] = hB;
    }
    if (kt + 2 < NT) stageW(cur, kt + 2);  // flies for a full kt
    if (kt == NT - 2) stageG();            // into buf0; kt=NT-1 reads buf1
    asm volatile("s_waitcnt lgkmcnt(0)" ::: "memory");
    if (kt == NT - 1)
      asm volatile("s_waitcnt vmcnt(0)" ::: "memory");  // G landed
    MEMFENCE;
    __builtin_amdgcn_s_barrier();
    MEMFENCE;
  }

  // ---- xo = G * multi per group; relu+max fused ----
  f32x4 xmax[4][2];
#pragma unroll
  for (int t = 0; t < 4; ++t)
#pragma unroll
    for (int u = 0; u < 2; ++u) xmax[t][u] = f32x4{0.f, 0.f, 0.f, 0.f};

#pragma unroll
  for (int g = 0; g < 4; ++g) {
    // B-frags from acc[g] in-register; shared k-slot bijection:
    // step s, lane-group gq, slot i -> j = 16s + 4gq + (i&3) + 32*(i>>2)
    abfrag bb[2][2];
#pragma unroll
    for (int s = 0; s < 2; ++s)
#pragma unroll
      for (int u = 0; u < 2; ++u) {
        abfrag t8;
#pragma unroll
        for (int r = 0; r < 4; ++r) {
          t8[r]     = (short)f2bf(acc[g][s][u][r]);
          t8[4 + r] = (short)f2bf(acc[g][s + 2][u][r]);
        }
        bb[s][u] = t8;
      }
    f32x4 xg[4][2];
#pragma unroll
    for (int t = 0; t < 4; ++t)
#pragma unroll
      for (int u = 0; u < 2; ++u) xg[t][u] = f32x4{0.f, 0.f, 0.f, 0.f};
#pragma unroll
    for (int t = 0; t < 4; ++t) {
      const short* grow = &lgv[nl][g][16 * t + l15][0];
#pragma unroll
      for (int s = 0; s < 2; ++s) {
        const int slot = 2 * s + (gq >> 1);
        const int e1 = ((slot ^ l7) << 3) + ((gq & 1) << 2);
        const int e2 = (((slot + 4) ^ l7) << 3) + ((gq & 1) << 2);
        s16x4 alo = *(const s16x4*)(grow + e1);
        s16x4 ahi = *(const s16x4*)(grow + e2);
        abfrag a;
#pragma unroll
        for (int j = 0; j < 4; ++j) { a[j] = alo[j]; a[4 + j] = ahi[j]; }
#pragma unroll
        for (int u = 0; u < 2; ++u) xg[t][u] = MFMA(a, bb[s][u], xg[t][u]);
      }
    }
#pragma unroll
    for (int t = 0; t < 4; ++t)
#pragma unroll
      for (int u = 0; u < 2; ++u)
#pragma unroll
        for (int r = 0; r < 4; ++r)
          xmax[t][u][r] = fmaxf(xmax[t][u][r], xg[t][u][r]);  // init 0 => relu
  }

  // ---- residual + store (C/D layout m89: col=lane&15, row=(lane>>4)*4+reg) --
#pragma unroll
  for (int t = 0; t < 4; ++t)
#pragma unroll
    for (int u = 0; u < 2; ++u)
#pragma unroll
      for (int r = 0; r < 4; ++r) {
        const int m = 16 * t + 4 * gq + r;
        const int d = pc0 + 32 * wv + 16 * u + l15;
        float v = xmax[t][u][r];
        if constexpr (RES) v += bf2f(hin[(size_t)(n * 64 + m) * C + d]);
        hout[(size_t)(n * 64 + m) * 512 + d] = f2bf(v);
      }
}

// ---------------- final linear head (unchanged) ----------------
__global__ __launch_bounds__(256, 2) void final_kernel(
    const unsigned short* __restrict__ hin,  // [128][64][512] bf16
    const float* __restrict__ w1,            // [128][512]
    const float* __restrict__ b1,            // [128]
    const float* __restrict__ w2,            // [128]
    const float* __restrict__ b2,            // [1]
    float* __restrict__ out) {               // [128][64]
  constexpr int KT = 64, LW = 72, C = 512, NT = C / KT;
  __shared__ short sh_h[2][64][LW];
  __shared__ short sh_w[2][128][LW];
  __shared__ float red[4][64];
  const int tid = threadIdx.x;
  const int wv  = tid >> 6;
  const int l15 = tid & 15;
  const int gq  = (tid >> 4) & 3;
  const int n   = blockIdx.x;
  const int srow = tid >> 3;
  const int scol = (tid & 7) * 8;
  const unsigned short* hsrc = hin + (size_t)n * 64 * C;

  f32x4 acc[4][2];
#pragma unroll
  for (int t = 0; t < 4; ++t)
#pragma unroll
    for (int u = 0; u < 2; ++u) acc[t][u] = f32x4{0.f, 0.f, 0.f, 0.f};

  i32x4 hr[2], wr[4];
#pragma unroll
  for (int p = 0; p < 2; ++p)
    hr[p] = *(const i32x4*)(hsrc + (srow + p * 32) * C + scol);
#pragma unroll
  for (int p = 0; p < 4; ++p) {  // fp32 w1 -> bf16 in-stage
    const float* s = w1 + (srow + p * 32) * C + scol;
    f32x4 v0 = *(const f32x4*)s;
    f32x4 v1 = *(const f32x4*)(s + 4);
    s16x8 o;
#pragma unroll
    for (int j = 0; j < 4; ++j) { o[j] = (short)f2bf(v0[j]); o[4 + j] = (short)f2bf(v1[j]); }
    wr[p] = __builtin_bit_cast(i32x4, o);
  }
#pragma unroll
  for (int p = 0; p < 2; ++p) *(i32x4*)&sh_h[0][srow + p * 32][scol] = hr[p];
#pragma unroll
  for (int p = 0; p < 4; ++p) *(i32x4*)&sh_w[0][srow + p * 32][scol] = wr[p];

  for (int kt = 0; kt < NT; ++kt) {
    const int cur = kt & 1;
    if (kt + 1 < NT) {
#pragma unroll
      for (int p = 0; p < 2; ++p)
        hr[p] = *(const i32x4*)(hsrc + (srow + p * 32) * C + (kt + 1) * KT + scol);
#pragma unroll
      for (int p = 0; p < 4; ++p) {
        const float* s = w1 + (srow + p * 32) * C + (kt + 1) * KT + scol;
        f32x4 v0 = *(const f32x4*)s;
        f32x4 v1 = *(const f32x4*)(s + 4);
        s16x8 o;
#pragma unroll
        for (int j = 0; j < 4; ++j) { o[j] = (short)f2bf(v0[j]); o[4 + j] = (short)f2bf(v1[j]); }
        wr[p] = __builtin_bit_cast(i32x4, o);
      }
    }
    __syncthreads();
#pragma unroll
    for (int ks = 0; ks < 2; ++ks) {
      abfrag a[4], b[2];
#pragma unroll
      for (int t = 0; t < 4; ++t)
        a[t] = *(const abfrag*)&sh_h[cur][16 * t + l15][ks * 32 + gq * 8];
#pragma unroll
      for (int u = 0; u < 2; ++u)
        b[u] = *(const abfrag*)&sh_w[cur][32 * wv + 16 * u + l15][ks * 32 + gq * 8];
#pragma unroll
      for (int t = 0; t < 4; ++t)
#pragma unroll
        for (int u = 0; u < 2; ++u) acc[t][u] = MFMA(a[t], b[u], acc[t][u]);
    }
    if (kt + 1 < NT) {
#pragma unroll
      for (int p = 0; p < 2; ++p) *(i32x4*)&sh_h[1 - cur][srow + p * 32][scol] = hr[p];
#pragma unroll
      for (int p = 0; p < 4; ++p) *(i32x4*)&sh_w[1 - cur][srow + p * 32][scol] = wr[p];
    }
  }

  float b1v[2], w2v[2];
#pragma unroll
  for (int u = 0; u < 2; ++u) {
    b1v[u] = b1[32 * wv + 16 * u + l15];
    w2v[u] = w2[32 * wv + 16 * u + l15];
  }
  float part[4][4];
#pragma unroll
  for (int t = 0; t < 4; ++t)
#pragma unroll
    for (int r = 0; r < 4; ++r) {
      float s0 = 0.f;
#pragma unroll
      for (int u = 0; u < 2; ++u)
        s0 += fmaxf(acc[t][u][r] + b1v[u], 0.f) * w2v[u];
      part[t][r] = s0;
    }
#pragma unroll
  for (int t = 0; t < 4; ++t)
#pragma unroll
    for (int r = 0; r < 4; ++r)
#pragma unroll
      for (int msk = 1; msk < 16; msk <<= 1)
        part[t][r] += __shfl_xor(part[t][r], msk);
  if (l15 == 0) {
#pragma unroll
    for (int t = 0; t < 4; ++t)
#pragma unroll
      for (int r = 0; r < 4; ++r) red[wv][16 * t + 4 * gq + r] = part[t][r];
  }
  __syncthreads();
  if (tid < 64)
    out[(size_t)n * 64 + tid] =
        red[0][tid] + red[1][tid] + red[2][tid] + red[3][tid] + b2[0];
}

// ---------------- host ----------------
extern "C" void kernel_launch(void* const* d_in, const int* in_sizes, int n_in,
                              void* d_out, int out_size, void* d_ws, size_t ws_size,
                              hipStream_t stream) {
  const float* G   = (const float*)d_in[0];
  const float* x   = (const float*)d_in[1];
  const float* W0  = (const float*)d_in[2];
  const float* b0  = (const float*)d_in[3];
  const float* W   = (const float*)d_in[4];
  const float* b   = (const float*)d_in[5];
  const float* l1w = (const float*)d_in[6];
  const float* l1b = (const float*)d_in[7];
  const float* l2w = (const float*)d_in[8];
  const float* l2b = (const float*)d_in[9];
  float* out = (float*)d_out;

  char* p = (char*)d_ws;
  unsigned short* W0b = (unsigned short*)p; p += (size_t)4 * 512 * 128 * 2;
  unsigned short* Wb  = (unsigned short*)p; p += (size_t)7 * 4 * 512 * 512 * 2;
  unsigned short* Gb  = (unsigned short*)p; p += (size_t)128 * 4 * 64 * 64 * 2;
  unsigned short* xb  = (unsigned short*)p; p += (size_t)128 * 64 * 128 * 2;
  unsigned short* hA  = (unsigned short*)p; p += (size_t)128 * 64 * 512 * 2;
  unsigned short* hB  = (unsigned short*)p; p += (size_t)128 * 64 * 512 * 2;
  // total ws use: 38,273,024 bytes

  // one fused conversion: dsts (W0b,Wb,Gb,xb) are contiguous
  const int n0 = 4 * 512 * 128 / 4;
  const int n1 = 7 * 4 * 512 * 512 / 4;
  const int n2 = 128 * 4 * 64 * 64 / 4;
  const int n3 = 128 * 64 * 128 / 4;
  f2bf_multi<<<2048, 256, 0, stream>>>(W0, n0, W, n1, G, n2, x, n3, W0b);

  gml_layer_kernel<128, false><<<256, 512, 0, stream>>>(xb, W0b, b0, Gb, hA);
  const unsigned short* src = hA;
  unsigned short* dst = hB;
  for (int i = 0; i < 7; ++i) {
    gml_layer_kernel<512, true><<<256, 512, 0, stream>>>(
        src, Wb + (size_t)i * 4 * 512 * 512, b + (size_t)i * 4 * 512, Gb, dst);
    const unsigned short* t = src; src = dst; dst = (unsigned short*)t;
  }
  final_kernel<<<128, 256, 0, stream>>>(src, l1w, l1b, l2w, l2b, out);
}

// Round 6
// 215.095 us; speedup vs baseline: 1.5026x; 1.1451x over previous
//
#include <hip/hip_runtime.h>

typedef float f32x4 __attribute__((ext_vector_type(4)));
typedef short s16x8 __attribute__((ext_vector_type(8)));
typedef short s16x4 __attribute__((ext_vector_type(4)));
typedef int   i32x4 __attribute__((ext_vector_type(4)));

using abfrag = s16x8;  // 8 bf16 = 4 VGPRs

#define DI __device__ __forceinline__

DI unsigned short f2bf(float x) {  // RNE float->bf16
  unsigned u = __builtin_bit_cast(unsigned, x);
  u += 0x7fffu + ((u >> 16) & 1u);
  return (unsigned short)(u >> 16);
}
DI float bf2f(unsigned short h) {
  return __builtin_bit_cast(float, ((unsigned)h) << 16);
}

DI f32x4 MFMA(abfrag a, abfrag b, f32x4 c) {
  return __builtin_amdgcn_mfma_f32_16x16x32_bf16(a, b, c, 0, 0, 0);
}

// async global->LDS DMA, 16B/lane; LDS dest = wave-uniform base + lane*16
// (m104); per-lane source address carries the swizzle (m173).
DI void gld16(void* lds_base, const void* gsrc) {
  __builtin_amdgcn_global_load_lds(
      (const __attribute__((address_space(1))) unsigned int*)gsrc,
      (__attribute__((address_space(3))) unsigned int*)lds_base, 16, 0, 0);
}

#define MEMFENCE asm volatile("" ::: "memory")

// ---------------- fused fp32 -> bf16 conversion (4 sources, contiguous dst) --
__global__ void f2bf_multi(const float* __restrict__ s0, int n0,
                           const float* __restrict__ s1, int n1,
                           const float* __restrict__ s2, int n2,
                           const float* __restrict__ s3, int n3,
                           unsigned short* __restrict__ dst) {
  const int total = n0 + n1 + n2 + n3;  // vec4 units
  int i = blockIdx.x * blockDim.x + threadIdx.x;
  const int stride = gridDim.x * blockDim.x;
  for (; i < total; i += stride) {
    const float* s; int off;
    if (i < n0) { s = s0; off = i; }
    else if (i < n0 + n1) { s = s1; off = i - n0; }
    else if (i < n0 + n1 + n2) { s = s2; off = i - n0 - n1; }
    else { s = s3; off = i - n0 - n1 - n2; }
    f32x4 v = ((const f32x4*)s)[off];
    s16x4 o;
#pragma unroll
    for (int j = 0; j < 4; ++j) o[j] = (short)f2bf(v[j]);
    ((s16x4*)dst)[i] = o;
  }
}

// -------- fused gml layer (R6: homogeneous gld16 queue, counted vmcnt) ------
// block = 256 thr = 4 waves (nl = w>>1, wv = w&1); tile = 2 n x 64 cols.
// Wave (nl,wv): rows 0..63 of n=2nn+nl, cols [pc0+32wv, +32), all 4 groups.
// ALL staging via global_load_lds (W, h, G) -> vmcnt queue is homogeneous;
// counted vmcnt(8) drains [W(kt+1):8, h(kt+1):4], leaves W(kt+2):8 in flight
// one full kt (verified m201/T4 semantics). No ds_writes / plain global loads
// in the K-loop. Bias folded into epilogue (after K accumulation).
// LDS 80KB exactly -> 2 blocks/CU alternate compute vs stage.
template <int C, bool RES>
__global__ __launch_bounds__(256, 2) void gml_layer_kernel(
    const unsigned short* __restrict__ hin,   // [128][64][C] bf16
    const unsigned short* __restrict__ Wb,    // [4][512][C] bf16
    const float* __restrict__ bias,           // [4][512]
    const unsigned short* __restrict__ Gb,    // [128][4][64][64] bf16
    unsigned short* __restrict__ hout) {      // [128][64][512] bf16
  constexpr int NT = C / 64;
  __shared__ short lh[2][64][64];      // [nl][row][k] 16 KB, XOR-swizzled
  __shared__ short lw[2][4][64][64];   // [buf][g][col][k] 64 KB; G[nl]->lw[nl]

  const int tid  = threadIdx.x;
  const int w    = tid >> 6;
  const int lane = tid & 63;
  const int l15  = lane & 15;
  const int l7   = l15 & 7;
  const int gq   = (lane >> 4) & 3;
  const int nl   = w >> 1;
  const int wv   = w & 1;
  const int nn   = blockIdx.x & 63;
  const int pc0  = (blockIdx.x >> 6) * 64;
  const int n    = 2 * nn + nl;
  const int lrow = lane >> 3;
  const int s8   = lane & 7;
  const int lsoff = ((s8 ^ lrow) << 3);  // swizzled element offset (row&7==lrow)

  const unsigned short* hsrc = hin + (size_t)n * 64 * C;

  // wave w stages: its own nl's h rows [32wv,+32); W group g=w; G group g=w.
  auto stageH = [&](int kt) {  // 4 gld16
#pragma unroll
    for (int j = 0; j < 4; ++j)
      gld16(&lh[nl][32 * wv + 8 * j][0],
            hsrc + (size_t)(32 * wv + 8 * j + lrow) * C + kt * 64 + lsoff);
  };
  auto stageW = [&](int buf, int kt) {  // 8 gld16
#pragma unroll
    for (int j = 0; j < 8; ++j)
      gld16(&lw[buf][w][8 * j][0],
            Wb + (size_t)(w * 512 + pc0 + 8 * j + lrow) * C + kt * 64 + lsoff);
  };
  auto stageG = [&](int nl_) {  // 8 gld16: G[2nn+nl_][g=w] -> lw[nl_][w]
#pragma unroll
    for (int j = 0; j < 8; ++j)
      gld16(&lw[nl_][w][8 * j][0],
            Gb + (size_t)((2 * nn + nl_) * 4 + w) * 4096 + (8 * j + lrow) * 64 + lsoff);
  };

  f32x4 acc[4][4][2];
#pragma unroll
  for (int g = 0; g < 4; ++g)
#pragma unroll
    for (int t = 0; t < 4; ++t)
#pragma unroll
      for (int u = 0; u < 2; ++u) acc[g][t][u] = f32x4{0.f, 0.f, 0.f, 0.f};

  // ---- prologue: queue = [W(0):8][h(0):4][W(1):8]; drain 12 oldest ----
  stageW(0, 0);
  stageH(0);
  stageW(1, 1);
  asm volatile("s_waitcnt vmcnt(8)" ::: "memory");  // W(0)+h(0) landed
  MEMFENCE; __builtin_amdgcn_s_barrier(); MEMFENCE;

  for (int kt = 0; kt < NT; ++kt) {
    const int cur = kt & 1;
    // ---- compute on lh + lw[cur]; A-frags read once, reused over 4 groups --
#pragma unroll
    for (int ks = 0; ks < 2; ++ks) {
      const int so = ((4 * ks + gq) ^ l7) << 3;
      abfrag a[4];
#pragma unroll
      for (int t = 0; t < 4; ++t)
        a[t] = *(const abfrag*)&lh[nl][16 * t + l15][so];
#pragma unroll
      for (int g = 0; g < 4; ++g)
#pragma unroll
        for (int u = 0; u < 2; ++u) {
          const abfrag b = *(const abfrag*)&lw[cur][g][32 * wv + 16 * u + l15][so];
#pragma unroll
          for (int t = 0; t < 4; ++t) acc[g][t][u] = MFMA(a[t], b, acc[g][t][u]);
        }
    }
    MEMFENCE; __builtin_amdgcn_s_barrier(); MEMFENCE;  // readers of cur/lh done

    // ---- stage phase: all gld16, issued oldest-needed-first ----
    if (kt + 1 < NT) stageH(kt + 1);       // into lh (just-retired contents)
    if (kt + 2 < NT) stageW(cur, kt + 2);  // into retiring buf; flies 1 full kt
    if (kt == NT - 2) stageG(0);           // into lw[0] (just retired)
    if (kt == NT - 1) stageG(1);           // into lw[1] (just retired)

    if (kt + 1 < NT) {
      // queue: [W(kt+1):8][h(kt+1):4][W(kt+2) or G0:8] -> drain first 12
      asm volatile("s_waitcnt vmcnt(8)" ::: "memory");
    } else {
      asm volatile("s_waitcnt vmcnt(0)" ::: "memory");  // G fully landed
    }
    MEMFENCE; __builtin_amdgcn_s_barrier(); MEMFENCE;
  }

  // ---- bias (added to multi before G-apply; loads only issue here) ----
  float bv[4][2];
#pragma unroll
  for (int g = 0; g < 4; ++g)
#pragma unroll
    for (int u = 0; u < 2; ++u)
      bv[g][u] = bias[g * 512 + pc0 + 32 * wv + 16 * u + l15];

  // ---- xo = G * multi per group; relu+max fused ----
  f32x4 xmax[4][2];
#pragma unroll
  for (int t = 0; t < 4; ++t)
#pragma unroll
    for (int u = 0; u < 2; ++u) xmax[t][u] = f32x4{0.f, 0.f, 0.f, 0.f};

#pragma unroll
  for (int g = 0; g < 4; ++g) {
    // B-frags from acc[g]+bias in-register; shared k-slot bijection:
    // step s, lane-group gq, slot i -> j = 16s + 4gq + (i&3) + 32*(i>>2)
    abfrag bb[2][2];
#pragma unroll
    for (int s = 0; s < 2; ++s)
#pragma unroll
      for (int u = 0; u < 2; ++u) {
        abfrag t8;
#pragma unroll
        for (int r = 0; r < 4; ++r) {
          t8[r]     = (short)f2bf(acc[g][s][u][r] + bv[g][u]);
          t8[4 + r] = (short)f2bf(acc[g][s + 2][u][r] + bv[g][u]);
        }
        bb[s][u] = t8;
      }
    f32x4 xg[4][2];
#pragma unroll
    for (int t = 0; t < 4; ++t)
#pragma unroll
      for (int u = 0; u < 2; ++u) xg[t][u] = f32x4{0.f, 0.f, 0.f, 0.f};
#pragma unroll
    for (int t = 0; t < 4; ++t) {
      const short* grow = &lw[nl][g][16 * t + l15][0];
#pragma unroll
      for (int s = 0; s < 2; ++s) {
        const int slot = 2 * s + (gq >> 1);
        const int e1 = ((slot ^ l7) << 3) + ((gq & 1) << 2);
        const int e2 = (((slot + 4) ^ l7) << 3) + ((gq & 1) << 2);
        s16x4 alo = *(const s16x4*)(grow + e1);
        s16x4 ahi = *(const s16x4*)(grow + e2);
        abfrag a;
#pragma unroll
        for (int j = 0; j < 4; ++j) { a[j] = alo[j]; a[4 + j] = ahi[j]; }
#pragma unroll
        for (int u = 0; u < 2; ++u) xg[t][u] = MFMA(a, bb[s][u], xg[t][u]);
      }
    }
#pragma unroll
    for (int t = 0; t < 4; ++t)
#pragma unroll
      for (int u = 0; u < 2; ++u)
#pragma unroll
        for (int r = 0; r < 4; ++r)
          xmax[t][u][r] = fmaxf(xmax[t][u][r], xg[t][u][r]);  // init 0 => relu
  }

  // ---- residual + store (C/D layout m89: col=lane&15, row=(lane>>4)*4+reg) --
#pragma unroll
  for (int t = 0; t < 4; ++t)
#pragma unroll
    for (int u = 0; u < 2; ++u)
#pragma unroll
      for (int r = 0; r < 4; ++r) {
        const int m = 16 * t + 4 * gq + r;
        const int d = pc0 + 32 * wv + 16 * u + l15;
        float v = xmax[t][u][r];
        if constexpr (RES) v += bf2f(hin[(size_t)(n * 64 + m) * C + d]);
        hout[(size_t)(n * 64 + m) * 512 + d] = f2bf(v);
      }
}

// ---------------- final linear head (unchanged) ----------------
__global__ __launch_bounds__(256, 2) void final_kernel(
    const unsigned short* __restrict__ hin,  // [128][64][512] bf16
    const float* __restrict__ w1,            // [128][512]
    const float* __restrict__ b1,            // [128]
    const float* __restrict__ w2,            // [128]
    const float* __restrict__ b2,            // [1]
    float* __restrict__ out) {               // [128][64]
  constexpr int KT = 64, LW = 72, C = 512, NT = C / KT;
  __shared__ short sh_h[2][64][LW];
  __shared__ short sh_w[2][128][LW];
  __shared__ float red[4][64];
  const int tid = threadIdx.x;
  const int wv  = tid >> 6;
  const int l15 = tid & 15;
  const int gq  = (tid >> 4) & 3;
  const int n   = blockIdx.x;
  const int srow = tid >> 3;
  const int scol = (tid & 7) * 8;
  const unsigned short* hsrc = hin + (size_t)n * 64 * C;

  f32x4 acc[4][2];
#pragma unroll
  for (int t = 0; t < 4; ++t)
#pragma unroll
    for (int u = 0; u < 2; ++u) acc[t][u] = f32x4{0.f, 0.f, 0.f, 0.f};

  i32x4 hr[2], wr[4];
#pragma unroll
  for (int p = 0; p < 2; ++p)
    hr[p] = *(const i32x4*)(hsrc + (srow + p * 32) * C + scol);
#pragma unroll
  for (int p = 0; p < 4; ++p) {  // fp32 w1 -> bf16 in-stage
    const float* s = w1 + (srow + p * 32) * C + scol;
    f32x4 v0 = *(const f32x4*)s;
    f32x4 v1 = *(const f32x4*)(s + 4);
    s16x8 o;
#pragma unroll
    for (int j = 0; j < 4; ++j) { o[j] = (short)f2bf(v0[j]); o[4 + j] = (short)f2bf(v1[j]); }
    wr[p] = __builtin_bit_cast(i32x4, o);
  }
#pragma unroll
  for (int p = 0; p < 2; ++p) *(i32x4*)&sh_h[0][srow + p * 32][scol] = hr[p];
#pragma unroll
  for (int p = 0; p < 4; ++p) *(i32x4*)&sh_w[0][srow + p * 32][scol] = wr[p];

  for (int kt = 0; kt < NT; ++kt) {
    const int cur = kt & 1;
    if (kt + 1 < NT) {
#pragma unroll
      for (int p = 0; p < 2; ++p)
        hr[p] = *(const i32x4*)(hsrc + (srow + p * 32) * C + (kt + 1) * KT + scol);
#pragma unroll
      for (int p = 0; p < 4; ++p) {
        const float* s = w1 + (srow + p * 32) * C + (kt + 1) * KT + scol;
        f32x4 v0 = *(const f32x4*)s;
        f32x4 v1 = *(const f32x4*)(s + 4);
        s16x8 o;
#pragma unroll
        for (int j = 0; j < 4; ++j) { o[j] = (short)f2bf(v0[j]); o[4 + j] = (short)f2bf(v1[j]); }
        wr[p] = __builtin_bit_cast(i32x4, o);
      }
    }
    __syncthreads();
#pragma unroll
    for (int ks = 0; ks < 2; ++ks) {
      abfrag a[4], b[2];
#pragma unroll
      for (int t = 0; t < 4; ++t)
        a[t] = *(const abfrag*)&sh_h[cur][16 * t + l15][ks * 32 + gq * 8];
#pragma unroll
      for (int u = 0; u < 2; ++u)
        b[u] = *(const abfrag*)&sh_w[cur][32 * wv + 16 * u + l15][ks * 32 + gq * 8];
#pragma unroll
      for (int t = 0; t < 4; ++t)
#pragma unroll
        for (int u = 0; u < 2; ++u) acc[t][u] = MFMA(a[t], b[u], acc[t][u]);
    }
    if (kt + 1 < NT) {
#pragma unroll
      for (int p = 0; p < 2; ++p) *(i32x4*)&sh_h[1 - cur][srow + p * 32][scol] = hr[p];
#pragma unroll
      for (int p = 0; p < 4; ++p) *(i32x4*)&sh_w[1 - cur][srow + p * 32][scol] = wr[p];
    }
  }

  float b1v[2], w2v[2];
#pragma unroll
  for (int u = 0; u < 2; ++u) {
    b1v[u] = b1[32 * wv + 16 * u + l15];
    w2v[u] = w2[32 * wv + 16 * u + l15];
  }
  float part[4][4];
#pragma unroll
  for (int t = 0; t < 4; ++t)
#pragma unroll
    for (int r = 0; r < 4; ++r) {
      float s0 = 0.f;
#pragma unroll
      for (int u = 0; u < 2; ++u)
        s0 += fmaxf(acc[t][u][r] + b1v[u], 0.f) * w2v[u];
      part[t][r] = s0;
    }
#pragma unroll
  for (int t = 0; t < 4; ++t)
#pragma unroll
    for (int r = 0; r < 4; ++r)
#pragma unroll
      for (int msk = 1; msk < 16; msk <<= 1)
        part[t][r] += __shfl_xor(part[t][r], msk);
  if (l15 == 0) {
#pragma unroll
    for (int t = 0; t < 4; ++t)
#pragma unroll
      for (int r = 0; r < 4; ++r) red[wv][16 * t + 4 * gq + r] = part[t][r];
  }
  __syncthreads();
  if (tid < 64)
    out[(size_t)n * 64 + tid] =
        red[0][tid] + red[1][tid] + red[2][tid] + red[3][tid] + b2[0];
}

// ---------------- host ----------------
extern "C" void kernel_launch(void* const* d_in, const int* in_sizes, int n_in,
                              void* d_out, int out_size, void* d_ws, size_t ws_size,
                              hipStream_t stream) {
  const float* G   = (const float*)d_in[0];
  const float* x   = (const float*)d_in[1];
  const float* W0  = (const float*)d_in[2];
  const float* b0  = (const float*)d_in[3];
  const float* W   = (const float*)d_in[4];
  const float* b   = (const float*)d_in[5];
  const float* l1w = (const float*)d_in[6];
  const float* l1b = (const float*)d_in[7];
  const float* l2w = (const float*)d_in[8];
  const float* l2b = (const float*)d_in[9];
  float* out = (float*)d_out;

  char* p = (char*)d_ws;
  unsigned short* W0b = (unsigned short*)p; p += (size_t)4 * 512 * 128 * 2;
  unsigned short* Wb  = (unsigned short*)p; p += (size_t)7 * 4 * 512 * 512 * 2;
  unsigned short* Gb  = (unsigned short*)p; p += (size_t)128 * 4 * 64 * 64 * 2;
  unsigned short* xb  = (unsigned short*)p; p += (size_t)128 * 64 * 128 * 2;
  unsigned short* hA  = (unsigned short*)p; p += (size_t)128 * 64 * 512 * 2;
  unsigned short* hB  = (unsigned short*)p; p += (size_t)128 * 64 * 512 * 2;
  // total ws use: 38,273,024 bytes

  // one fused conversion: dsts (W0b,Wb,Gb,xb) are contiguous
  const int n0 = 4 * 512 * 128 / 4;
  const int n1 = 7 * 4 * 512 * 512 / 4;
  const int n2 = 128 * 4 * 64 * 64 / 4;
  const int n3 = 128 * 64 * 128 / 4;
  f2bf_multi<<<2048, 256, 0, stream>>>(W0, n0, W, n1, G, n2, x, n3, W0b);

  gml_layer_kernel<128, false><<<512, 256, 0, stream>>>(xb, W0b, b0, Gb, hA);
  const unsigned short* src = hA;
  unsigned short* dst = hB;
  for (int i = 0; i < 7; ++i) {
    gml_layer_kernel<512, true><<<512, 256, 0, stream>>>(
        src, Wb + (size_t)i * 4 * 512 * 512, b + (size_t)i * 4 * 512, Gb, dst);
    const unsigned short* t = src; src = dst; dst = (unsigned short*)t;
  }
  final_kernel<<<128, 256, 0, stream>>>(src, l1w, l1b, l2w, l2b, out);
}